// Round 1
// baseline (21802.252 us; speedup 1.0000x reference)
//
#include <hip/hip_runtime.h>
#include <hip/hip_bf16.h>

#define N_NODES   100000
#define DFEAT     256      // DIN == DOUT == 256
#define GEMM_ROWS 8        // rows of X per block in the GEMM

// ---------------------------------------------------------------------------
// Kernel 1: out[n][f] = bias[f]  (float4 grid-stride)
// ---------------------------------------------------------------------------
__global__ void init_bias_kernel(float* __restrict__ out,
                                 const float* __restrict__ bias,
                                 long n4 /* total float4 count */) {
    long i = (long)blockIdx.x * blockDim.x + threadIdx.x;
    long stride = (long)gridDim.x * blockDim.x;
    for (; i < n4; i += stride) {
        int f4 = (int)(i & 63);   // 64 float4 per 256-wide row
        float4 b = reinterpret_cast<const float4*>(bias)[f4];
        reinterpret_cast<float4*>(out)[i] = b;
    }
}

// ---------------------------------------------------------------------------
// Kernel 2: Y = X @ W   (fp32, X tile in LDS, W streamed from L2)
// block: 256 threads, handles GEMM_ROWS rows of X.
// thread (tx = tid&63 -> 4 consecutive output cols, ty = tid>>6 -> 2 rows)
// ---------------------------------------------------------------------------
__global__ __launch_bounds__(256) void gemm_xw_kernel(
        const float* __restrict__ X, const float* __restrict__ W,
        float* __restrict__ Y) {
    __shared__ float Xs[GEMM_ROWS][DFEAT];

    long row0 = (long)blockIdx.x * GEMM_ROWS;

    // Stage X tile: GEMM_ROWS*256 floats = 512 float4, 2 per thread.
    const float4* Xg = reinterpret_cast<const float4*>(X + row0 * DFEAT);
    float4* Xs4 = reinterpret_cast<float4*>(&Xs[0][0]);
    Xs4[threadIdx.x]       = Xg[threadIdx.x];
    Xs4[threadIdx.x + 256] = Xg[threadIdx.x + 256];
    __syncthreads();

    const int tx = threadIdx.x & 63;
    const int ty = threadIdx.x >> 6;
    const int c  = tx * 4;
    const int r0 = ty * 2;
    const int r1 = r0 + 1;

    float4 acc0 = {0.f, 0.f, 0.f, 0.f};
    float4 acc1 = {0.f, 0.f, 0.f, 0.f};

    #pragma unroll 8
    for (int k = 0; k < DFEAT; ++k) {
        float4 w = *reinterpret_cast<const float4*>(W + (size_t)k * DFEAT + c);
        float xa = Xs[r0][k];
        float xb = Xs[r1][k];
        acc0.x = fmaf(xa, w.x, acc0.x);
        acc0.y = fmaf(xa, w.y, acc0.y);
        acc0.z = fmaf(xa, w.z, acc0.z);
        acc0.w = fmaf(xa, w.w, acc0.w);
        acc1.x = fmaf(xb, w.x, acc1.x);
        acc1.y = fmaf(xb, w.y, acc1.y);
        acc1.z = fmaf(xb, w.z, acc1.z);
        acc1.w = fmaf(xb, w.w, acc1.w);
    }

    *reinterpret_cast<float4*>(Y + (row0 + r0) * DFEAT + c) = acc0;
    *reinterpret_cast<float4*>(Y + (row0 + r1) * DFEAT + c) = acc1;
}

// ---------------------------------------------------------------------------
// Kernel 3: out[row] += val * Y[col]   per COO edge, one wave per edge.
// lane l owns features [4l, 4l+4): float4 gather + 4 hw fp32 atomics.
// ---------------------------------------------------------------------------
__global__ __launch_bounds__(256) void spmm_scatter_kernel(
        const int*   __restrict__ rows,
        const int*   __restrict__ cols,
        const float* __restrict__ vals,
        const float* __restrict__ Y,
        float*       __restrict__ out,
        int nnz) {
    const int lane = threadIdx.x & 63;
    long wid = (long)blockIdx.x * (blockDim.x >> 6) + (threadIdx.x >> 6);
    long nw  = (long)gridDim.x * (blockDim.x >> 6);

    for (long e = wid; e < nnz; e += nw) {
        int   r = rows[e];
        int   c = cols[e];
        float v = vals[e];
        float4 y = *reinterpret_cast<const float4*>(Y + (size_t)c * DFEAT + lane * 4);
        float* o = out + (size_t)r * DFEAT + lane * 4;
        unsafeAtomicAdd(o + 0, v * y.x);
        unsafeAtomicAdd(o + 1, v * y.y);
        unsafeAtomicAdd(o + 2, v * y.z);
        unsafeAtomicAdd(o + 3, v * y.w);
    }
}

extern "C" void kernel_launch(void* const* d_in, const int* in_sizes, int n_in,
                              void* d_out, int out_size, void* d_ws, size_t ws_size,
                              hipStream_t stream) {
    const float* X       = (const float*)d_in[0];
    const int*   L_rows  = (const int*)  d_in[1];
    const int*   L_cols  = (const int*)  d_in[2];
    const float* L_vals  = (const float*)d_in[3];
    const int*   L3_rows = (const int*)  d_in[4];
    const int*   L3_cols = (const int*)  d_in[5];
    const float* L3_vals = (const float*)d_in[6];
    const float* W       = (const float*)d_in[7];
    const float* bias    = (const float*)d_in[8];

    const int N   = in_sizes[0] / DFEAT;   // 100000
    const int nnz = in_sizes[1];           // 3200000

    float* Y   = (float*)d_ws;             // [N, 256] fp32 = 102.4 MB scratch
    float* out = (float*)d_out;

    // 1) out = bias (broadcast)
    long n4 = (long)N * (DFEAT / 4);
    init_bias_kernel<<<4096, 256, 0, stream>>>(out, bias, n4);

    // 2) Y = X @ W
    gemm_xw_kernel<<<N / GEMM_ROWS, 256, 0, stream>>>(X, W, Y);

    // 3) out += L @ Y ; out += L3 @ Y
    spmm_scatter_kernel<<<4096, 256, 0, stream>>>(L_rows, L_cols, L_vals, Y, out, nnz);
    spmm_scatter_kernel<<<4096, 256, 0, stream>>>(L3_rows, L3_cols, L3_vals, Y, out, nnz);
}

// Round 2
// 2312.840 us; speedup vs baseline: 9.4266x; 9.4266x over previous
//
#include <hip/hip_runtime.h>
#include <hip/hip_bf16.h>

#define DFEAT     256      // DIN == DOUT == 256
#define GEMM_ROWS 8        // rows of X per block in the GEMM
#define SCAN_T    1024

// ---------------------------------------------------------------------------
// Kernel 1: Y = X @ W   (fp32, X tile in LDS, W streamed from L2)
// ---------------------------------------------------------------------------
__global__ __launch_bounds__(256) void gemm_xw_kernel(
        const float* __restrict__ X, const float* __restrict__ W,
        float* __restrict__ Y) {
    __shared__ float Xs[GEMM_ROWS][DFEAT];

    long row0 = (long)blockIdx.x * GEMM_ROWS;

    const float4* Xg = reinterpret_cast<const float4*>(X + row0 * DFEAT);
    float4* Xs4 = reinterpret_cast<float4*>(&Xs[0][0]);
    Xs4[threadIdx.x]       = Xg[threadIdx.x];
    Xs4[threadIdx.x + 256] = Xg[threadIdx.x + 256];
    __syncthreads();

    const int tx = threadIdx.x & 63;
    const int ty = threadIdx.x >> 6;
    const int c  = tx * 4;
    const int r0 = ty * 2;
    const int r1 = r0 + 1;

    float4 acc0 = {0.f, 0.f, 0.f, 0.f};
    float4 acc1 = {0.f, 0.f, 0.f, 0.f};

    #pragma unroll 8
    for (int k = 0; k < DFEAT; ++k) {
        float4 w = *reinterpret_cast<const float4*>(W + (size_t)k * DFEAT + c);
        float xa = Xs[r0][k];
        float xb = Xs[r1][k];
        acc0.x = fmaf(xa, w.x, acc0.x);
        acc0.y = fmaf(xa, w.y, acc0.y);
        acc0.z = fmaf(xa, w.z, acc0.z);
        acc0.w = fmaf(xa, w.w, acc0.w);
        acc1.x = fmaf(xb, w.x, acc1.x);
        acc1.y = fmaf(xb, w.y, acc1.y);
        acc1.z = fmaf(xb, w.z, acc1.z);
        acc1.w = fmaf(xb, w.w, acc1.w);
    }

    *reinterpret_cast<float4*>(Y + (row0 + r0) * DFEAT + c) = acc0;
    *reinterpret_cast<float4*>(Y + (row0 + r1) * DFEAT + c) = acc1;
}

// ---------------------------------------------------------------------------
// Kernel 2: row histogram over BOTH edge lists (int atomics on L2-resident
// 400 KB counter array — cheap)
// ---------------------------------------------------------------------------
__global__ __launch_bounds__(256) void hist_kernel(
        const int* __restrict__ rows1, const int* __restrict__ rows2,
        int nnz, int* __restrict__ counts) {
    long i = (long)blockIdx.x * blockDim.x + threadIdx.x;
    long stride = (long)gridDim.x * blockDim.x;
    long total = 2L * nnz;
    for (; i < total; i += stride) {
        int r = (i < nnz) ? rows1[i] : rows2[i - nnz];
        atomicAdd(&counts[r], 1);
    }
}

// ---------------------------------------------------------------------------
// Kernel 3: single-block exclusive scan of counts -> offsets (and cursor copy)
// ---------------------------------------------------------------------------
__global__ __launch_bounds__(SCAN_T) void scan_kernel(
        const int* __restrict__ counts, int* __restrict__ offsets,
        int* __restrict__ cursor, int n) {
    __shared__ int part[SCAN_T];
    int t = threadIdx.x;
    int chunk = (n + SCAN_T - 1) / SCAN_T;
    int lo = t * chunk;
    int hi = lo + chunk; if (hi > n) hi = n; if (lo > n) lo = n;

    int s = 0;
    for (int i = lo; i < hi; ++i) s += counts[i];
    part[t] = s;
    __syncthreads();

    // Hillis-Steele inclusive scan over the 1024 partials
    for (int d = 1; d < SCAN_T; d <<= 1) {
        int v = part[t];
        if (t >= d) v += part[t - d];
        __syncthreads();
        part[t] = v;
        __syncthreads();
    }
    int run = part[t] - s;   // exclusive prefix of this thread's chunk
    for (int i = lo; i < hi; ++i) {
        offsets[i] = run;
        cursor[i]  = run;
        run += counts[i];
    }
    if (t == SCAN_T - 1) offsets[n] = run;
}

// ---------------------------------------------------------------------------
// Kernel 4: scatter edges into CSR slots (position via int atomic on cursor)
// ---------------------------------------------------------------------------
__global__ __launch_bounds__(256) void scatter_kernel(
        const int* __restrict__ rows, const int* __restrict__ cols,
        const float* __restrict__ vals, int nnz,
        int* __restrict__ cursor, int* __restrict__ csr_col,
        float* __restrict__ csr_val) {
    long i = (long)blockIdx.x * blockDim.x + threadIdx.x;
    long stride = (long)gridDim.x * blockDim.x;
    for (; i < nnz; i += stride) {
        int r = rows[i];
        int pos = atomicAdd(&cursor[r], 1);
        csr_col[pos] = cols[i];
        csr_val[pos] = vals[i];
    }
}

// ---------------------------------------------------------------------------
// Kernel 5: CSR segment-sum SpMM. One wave per row; lane l owns float4 at
// col 4l. acc starts at bias; Y gathers are L3-served (Y = 102 MB < 256 MB).
// Single coalesced float4 store per row — no fp32 atomics anywhere.
// ---------------------------------------------------------------------------
__global__ __launch_bounds__(256) void spmm_csr_kernel(
        const int* __restrict__ offsets, const int* __restrict__ csr_col,
        const float* __restrict__ csr_val, const float* __restrict__ Y,
        const float* __restrict__ bias, float* __restrict__ out, int n) {
    const int lane = threadIdx.x & 63;
    long row = (long)blockIdx.x * 4 + (threadIdx.x >> 6);
    if (row >= n) return;

    int s = offsets[row];
    int e = offsets[row + 1];

    float4 acc = reinterpret_cast<const float4*>(bias)[lane];

    int i = s;
    // 2-edge unroll for load-latency overlap
    for (; i + 2 <= e; i += 2) {
        int   c0 = csr_col[i],     c1 = csr_col[i + 1];
        float v0 = csr_val[i],     v1 = csr_val[i + 1];
        float4 y0 = *reinterpret_cast<const float4*>(Y + (size_t)c0 * DFEAT + lane * 4);
        float4 y1 = *reinterpret_cast<const float4*>(Y + (size_t)c1 * DFEAT + lane * 4);
        acc.x = fmaf(v0, y0.x, acc.x); acc.x = fmaf(v1, y1.x, acc.x);
        acc.y = fmaf(v0, y0.y, acc.y); acc.y = fmaf(v1, y1.y, acc.y);
        acc.z = fmaf(v0, y0.z, acc.z); acc.z = fmaf(v1, y1.z, acc.z);
        acc.w = fmaf(v0, y0.w, acc.w); acc.w = fmaf(v1, y1.w, acc.w);
    }
    if (i < e) {
        int   c0 = csr_col[i];
        float v0 = csr_val[i];
        float4 y0 = *reinterpret_cast<const float4*>(Y + (size_t)c0 * DFEAT + lane * 4);
        acc.x = fmaf(v0, y0.x, acc.x);
        acc.y = fmaf(v0, y0.y, acc.y);
        acc.z = fmaf(v0, y0.z, acc.z);
        acc.w = fmaf(v0, y0.w, acc.w);
    }

    *reinterpret_cast<float4*>(out + row * DFEAT + lane * 4) = acc;
}

extern "C" void kernel_launch(void* const* d_in, const int* in_sizes, int n_in,
                              void* d_out, int out_size, void* d_ws, size_t ws_size,
                              hipStream_t stream) {
    const float* X       = (const float*)d_in[0];
    const int*   L_rows  = (const int*)  d_in[1];
    const int*   L_cols  = (const int*)  d_in[2];
    const float* L_vals  = (const float*)d_in[3];
    const int*   L3_rows = (const int*)  d_in[4];
    const int*   L3_cols = (const int*)  d_in[5];
    const float* L3_vals = (const float*)d_in[6];
    const float* W       = (const float*)d_in[7];
    const float* bias    = (const float*)d_in[8];

    const int N   = in_sizes[0] / DFEAT;   // 100000
    const int nnz = in_sizes[1];           // 3200000 per Laplacian

    // ---- workspace layout ----
    char* p = (char*)d_ws;
    float* Y = (float*)p;            p += (size_t)N * DFEAT * sizeof(float);  // 102.4 MB
    int* counts  = (int*)p;          p += (size_t)N * sizeof(int);
    int* offsets = (int*)p;          p += (size_t)(N + 1) * sizeof(int);
    int* cursor  = (int*)p;          p += (size_t)N * sizeof(int);
    p = (char*)(((uintptr_t)p + 15) & ~(uintptr_t)15);
    int*   csr_col = (int*)p;        p += (size_t)2 * nnz * sizeof(int);      // 25.6 MB
    float* csr_val = (float*)p;      /* 25.6 MB */

    float* out = (float*)d_out;

    // ---- CSR build (both Laplacians merged) ----
    hipMemsetAsync(counts, 0, (size_t)N * sizeof(int), stream);
    hist_kernel<<<2048, 256, 0, stream>>>(L_rows, L3_rows, nnz, counts);
    scan_kernel<<<1, SCAN_T, 0, stream>>>(counts, offsets, cursor, N);
    scatter_kernel<<<2048, 256, 0, stream>>>(L_rows, L_cols, L_vals, nnz,
                                             cursor, csr_col, csr_val);
    scatter_kernel<<<2048, 256, 0, stream>>>(L3_rows, L3_cols, L3_vals, nnz,
                                             cursor, csr_col, csr_val);

    // ---- dense Y = X @ W (overlaps nothing, but independent of CSR build) ----
    gemm_xw_kernel<<<N / GEMM_ROWS, 256, 0, stream>>>(X, W, Y);

    // ---- segment-sum SpMM: out = (L + L3) @ Y + bias ----
    spmm_csr_kernel<<<(N + 3) / 4, 256, 0, stream>>>(offsets, csr_col, csr_val,
                                                     Y, bias, out, N);
}

// Round 3
// 1746.308 us; speedup vs baseline: 12.4848x; 1.3244x over previous
//
#include <hip/hip_runtime.h>
#include <hip/hip_bf16.h>

#define DFEAT     256      // DIN == DOUT == 256
#define GEMM_ROWS 8        // rows of X per block in the GEMM
#define SCAN_BLK  1024

__device__ __forceinline__ float bf2f(unsigned short u) {
    return __uint_as_float(((unsigned)u) << 16);
}
__device__ __forceinline__ unsigned short f2bf(float f) {
    __hip_bfloat16 h = __float2bfloat16(f);   // RNE
    return *reinterpret_cast<unsigned short*>(&h);
}

// ---------------------------------------------------------------------------
// Kernel 1: Y = X @ W   (fp32 compute, bf16 store)
// ---------------------------------------------------------------------------
__global__ __launch_bounds__(256) void gemm_xw_kernel(
        const float* __restrict__ X, const float* __restrict__ W,
        unsigned short* __restrict__ Yb) {
    __shared__ float Xs[GEMM_ROWS][DFEAT];

    long row0 = (long)blockIdx.x * GEMM_ROWS;

    const float4* Xg = reinterpret_cast<const float4*>(X + row0 * DFEAT);
    float4* Xs4 = reinterpret_cast<float4*>(&Xs[0][0]);
    Xs4[threadIdx.x]       = Xg[threadIdx.x];
    Xs4[threadIdx.x + 256] = Xg[threadIdx.x + 256];
    __syncthreads();

    const int tx = threadIdx.x & 63;
    const int ty = threadIdx.x >> 6;
    const int c  = tx * 4;
    const int r0 = ty * 2;
    const int r1 = r0 + 1;

    float4 acc0 = {0.f, 0.f, 0.f, 0.f};
    float4 acc1 = {0.f, 0.f, 0.f, 0.f};

    #pragma unroll 8
    for (int k = 0; k < DFEAT; ++k) {
        float4 w = *reinterpret_cast<const float4*>(W + (size_t)k * DFEAT + c);
        float xa = Xs[r0][k];
        float xb = Xs[r1][k];
        acc0.x = fmaf(xa, w.x, acc0.x);
        acc0.y = fmaf(xa, w.y, acc0.y);
        acc0.z = fmaf(xa, w.z, acc0.z);
        acc0.w = fmaf(xa, w.w, acc0.w);
        acc1.x = fmaf(xb, w.x, acc1.x);
        acc1.y = fmaf(xb, w.y, acc1.y);
        acc1.z = fmaf(xb, w.z, acc1.z);
        acc1.w = fmaf(xb, w.w, acc1.w);
    }

    ushort4 o0 = { f2bf(acc0.x), f2bf(acc0.y), f2bf(acc0.z), f2bf(acc0.w) };
    ushort4 o1 = { f2bf(acc1.x), f2bf(acc1.y), f2bf(acc1.z), f2bf(acc1.w) };
    *reinterpret_cast<ushort4*>(Yb + (row0 + r0) * DFEAT + c) = o0;
    *reinterpret_cast<ushort4*>(Yb + (row0 + r1) * DFEAT + c) = o1;
}

// ---------------------------------------------------------------------------
// Kernel 2: row histogram over BOTH edge lists
// ---------------------------------------------------------------------------
__global__ __launch_bounds__(256) void hist_kernel(
        const int* __restrict__ rows1, const int* __restrict__ rows2,
        int nnz, int* __restrict__ counts) {
    long i = (long)blockIdx.x * blockDim.x + threadIdx.x;
    long stride = (long)gridDim.x * blockDim.x;
    long total = 2L * nnz;
    for (; i < total; i += stride) {
        int r = (i < nnz) ? rows1[i] : rows2[i - nnz];
        atomicAdd(&counts[r], 1);
    }
}

// ---------------------------------------------------------------------------
// Kernels 3a/3b/3c: multi-block exclusive scan of counts -> offsets, cursor
// ---------------------------------------------------------------------------
__global__ __launch_bounds__(SCAN_BLK) void scan_partial_kernel(
        const int* __restrict__ counts, int* __restrict__ partials, int n) {
    __shared__ int sdata[SCAN_BLK];
    int g = blockIdx.x * SCAN_BLK + threadIdx.x;
    sdata[threadIdx.x] = (g < n) ? counts[g] : 0;
    __syncthreads();
    for (int d = SCAN_BLK / 2; d > 0; d >>= 1) {
        if (threadIdx.x < d) sdata[threadIdx.x] += sdata[threadIdx.x + d];
        __syncthreads();
    }
    if (threadIdx.x == 0) partials[blockIdx.x] = sdata[0];
}

__global__ __launch_bounds__(128) void scan_top_kernel(
        int* __restrict__ partials, int nb) {
    __shared__ int s[128];
    int t = threadIdx.x;
    int v = (t < nb) ? partials[t] : 0;
    s[t] = v;
    __syncthreads();
    for (int d = 1; d < 128; d <<= 1) {
        int x = s[t];
        if (t >= d) x += s[t - d];
        __syncthreads();
        s[t] = x;
        __syncthreads();
    }
    if (t < nb) partials[t] = s[t] - v;   // exclusive prefix of block sums
}

__global__ __launch_bounds__(SCAN_BLK) void scan_final_kernel(
        const int* __restrict__ counts, const int* __restrict__ partials,
        int* __restrict__ offsets, int* __restrict__ cursor, int n) {
    __shared__ int s[SCAN_BLK];
    int t = threadIdx.x;
    int g = blockIdx.x * SCAN_BLK + t;
    int v = (g < n) ? counts[g] : 0;
    s[t] = v;
    __syncthreads();
    for (int d = 1; d < SCAN_BLK; d <<= 1) {
        int x = s[t];
        if (t >= d) x += s[t - d];
        __syncthreads();
        s[t] = x;
        __syncthreads();
    }
    if (g < n) {
        int excl = s[t] - v + partials[blockIdx.x];
        offsets[g] = excl;
        cursor[g]  = excl;
        if (g == n - 1) offsets[n] = excl + v;
    }
}

// ---------------------------------------------------------------------------
// Kernel 4: scatter BOTH edge lists into packed CSR slots {col, val}
// ---------------------------------------------------------------------------
__global__ __launch_bounds__(256) void scatter_kernel(
        const int* __restrict__ rows1, const int* __restrict__ cols1,
        const float* __restrict__ vals1,
        const int* __restrict__ rows2, const int* __restrict__ cols2,
        const float* __restrict__ vals2,
        int nnz, int* __restrict__ cursor, int2* __restrict__ csr) {
    long i = (long)blockIdx.x * blockDim.x + threadIdx.x;
    long stride = (long)gridDim.x * blockDim.x;
    long total = 2L * nnz;
    for (; i < total; i += stride) {
        int r, c; float v;
        if (i < nnz) { r = rows1[i]; c = cols1[i]; v = vals1[i]; }
        else         { long j = i - nnz; r = rows2[j]; c = cols2[j]; v = vals2[j]; }
        int pos = atomicAdd(&cursor[r], 1);
        int2 e; e.x = c; e.y = __float_as_int(v);
        csr[pos] = e;
    }
}

// ---------------------------------------------------------------------------
// Kernel 5: CSR segment-sum SpMM over bf16 Y. One wave per row; lane l owns
// cols [4l,4l+4) -> ushort4 (8B) gather per edge. No fp32 atomics.
// ---------------------------------------------------------------------------
__global__ __launch_bounds__(256) void spmm_csr_kernel(
        const int* __restrict__ offsets, const int2* __restrict__ csr,
        const unsigned short* __restrict__ Yb,
        const float* __restrict__ bias, float* __restrict__ out, int n) {
    const int lane = threadIdx.x & 63;
    long row = (long)blockIdx.x * 4 + (threadIdx.x >> 6);
    if (row >= n) return;

    int s = offsets[row];
    int e = offsets[row + 1];

    float4 acc = reinterpret_cast<const float4*>(bias)[lane];
    const int loff = lane * 4;

    int i = s;
    for (; i + 4 <= e; i += 4) {
        int2 e0 = csr[i], e1 = csr[i+1], e2 = csr[i+2], e3 = csr[i+3];
        ushort4 y0 = *reinterpret_cast<const ushort4*>(Yb + (size_t)e0.x * DFEAT + loff);
        ushort4 y1 = *reinterpret_cast<const ushort4*>(Yb + (size_t)e1.x * DFEAT + loff);
        ushort4 y2 = *reinterpret_cast<const ushort4*>(Yb + (size_t)e2.x * DFEAT + loff);
        ushort4 y3 = *reinterpret_cast<const ushort4*>(Yb + (size_t)e3.x * DFEAT + loff);
        float v0 = __int_as_float(e0.y), v1 = __int_as_float(e1.y);
        float v2 = __int_as_float(e2.y), v3 = __int_as_float(e3.y);
        acc.x = fmaf(v0, bf2f(y0.x), acc.x);
        acc.y = fmaf(v0, bf2f(y0.y), acc.y);
        acc.z = fmaf(v0, bf2f(y0.z), acc.z);
        acc.w = fmaf(v0, bf2f(y0.w), acc.w);
        acc.x = fmaf(v1, bf2f(y1.x), acc.x);
        acc.y = fmaf(v1, bf2f(y1.y), acc.y);
        acc.z = fmaf(v1, bf2f(y1.z), acc.z);
        acc.w = fmaf(v1, bf2f(y1.w), acc.w);
        acc.x = fmaf(v2, bf2f(y2.x), acc.x);
        acc.y = fmaf(v2, bf2f(y2.y), acc.y);
        acc.z = fmaf(v2, bf2f(y2.z), acc.z);
        acc.w = fmaf(v2, bf2f(y2.w), acc.w);
        acc.x = fmaf(v3, bf2f(y3.x), acc.x);
        acc.y = fmaf(v3, bf2f(y3.y), acc.y);
        acc.z = fmaf(v3, bf2f(y3.z), acc.z);
        acc.w = fmaf(v3, bf2f(y3.w), acc.w);
    }
    for (; i < e; ++i) {
        int2 e0 = csr[i];
        ushort4 y0 = *reinterpret_cast<const ushort4*>(Yb + (size_t)e0.x * DFEAT + loff);
        float v0 = __int_as_float(e0.y);
        acc.x = fmaf(v0, bf2f(y0.x), acc.x);
        acc.y = fmaf(v0, bf2f(y0.y), acc.y);
        acc.z = fmaf(v0, bf2f(y0.z), acc.z);
        acc.w = fmaf(v0, bf2f(y0.w), acc.w);
    }

    *reinterpret_cast<float4*>(out + row * DFEAT + loff) = acc;
}

extern "C" void kernel_launch(void* const* d_in, const int* in_sizes, int n_in,
                              void* d_out, int out_size, void* d_ws, size_t ws_size,
                              hipStream_t stream) {
    const float* X       = (const float*)d_in[0];
    const int*   L_rows  = (const int*)  d_in[1];
    const int*   L_cols  = (const int*)  d_in[2];
    const float* L_vals  = (const float*)d_in[3];
    const int*   L3_rows = (const int*)  d_in[4];
    const int*   L3_cols = (const int*)  d_in[5];
    const float* L3_vals = (const float*)d_in[6];
    const float* W       = (const float*)d_in[7];
    const float* bias    = (const float*)d_in[8];

    const int N   = in_sizes[0] / DFEAT;   // 100000
    const int nnz = in_sizes[1];           // 3200000 per Laplacian

    // ---- workspace layout ----
    char* p = (char*)d_ws;
    unsigned short* Yb = (unsigned short*)p;
    p += (size_t)N * DFEAT * sizeof(unsigned short);           // 51.2 MB
    int* counts   = (int*)p;  p += (size_t)N * sizeof(int);
    int* offsets  = (int*)p;  p += (size_t)(N + 1) * sizeof(int);
    int* cursor   = (int*)p;  p += (size_t)N * sizeof(int);
    int* partials = (int*)p;  p += 128 * sizeof(int);
    p = (char*)(((uintptr_t)p + 15) & ~(uintptr_t)15);
    int2* csr = (int2*)p;                                       // 51.2 MB

    float* out = (float*)d_out;

    const int nb = (N + SCAN_BLK - 1) / SCAN_BLK;   // 98 scan blocks

    // ---- CSR build (both Laplacians merged, packed {col,val}) ----
    hipMemsetAsync(counts, 0, (size_t)N * sizeof(int), stream);
    hist_kernel<<<2048, 256, 0, stream>>>(L_rows, L3_rows, nnz, counts);
    scan_partial_kernel<<<nb, SCAN_BLK, 0, stream>>>(counts, partials, N);
    scan_top_kernel<<<1, 128, 0, stream>>>(partials, nb);
    scan_final_kernel<<<nb, SCAN_BLK, 0, stream>>>(counts, partials, offsets, cursor, N);
    scatter_kernel<<<4096, 256, 0, stream>>>(L_rows, L_cols, L_vals,
                                             L3_rows, L3_cols, L3_vals,
                                             nnz, cursor, csr);

    // ---- dense Y = X @ W (bf16 output) ----
    gemm_xw_kernel<<<N / GEMM_ROWS, 256, 0, stream>>>(X, W, Yb);

    // ---- segment-sum SpMM: out = (L + L3) @ Y + bias ----
    spmm_csr_kernel<<<(N + 3) / 4, 256, 0, stream>>>(offsets, csr, Yb, bias, out, N);
}